// Round 19
// baseline (1106.824 us; speedup 1.0000x reference)
//
#include <hip/hip_runtime.h>
#include <hip/hip_bf16.h>
#include <cstdint>
#include <cstddef>

#define IN_FEATS 256
#define NUM_HEADS 8
#define HD 512     // NUM_HEADS*OUT_FEATS
#define CH 64      // edges per chunk in agg (covers deg<=64 in one chunk)
#define ELLCAP 128 // per-node edge capacity (Poisson(32): P(deg>=128) < 1e-40)

// measurement round 3
#define AGG_REPS 16
#define K1_REPS 12

typedef __attribute__((ext_vector_type(8))) short bf16x8;
typedef __attribute__((ext_vector_type(4))) float f32x4;

__device__ inline unsigned short bf16_bits(float f) {
    unsigned x = __float_as_uint(f);
    x += 0x7fffu + ((x >> 16) & 1u);  // RNE
    return (unsigned short)(x >> 16);
}

// ---------------- K0: zero deg | Wt transpose ----------------

__global__ __launch_bounds__(256) void k0_kernel(const float* __restrict__ W,
                                                 int* __restrict__ deg,
                                                 unsigned short* __restrict__ Wt,
                                                 int M) {
    const int b = blockIdx.x;
    const int t = threadIdx.x;
    if (b < 40) {
        int i = b * 256 + t;
        if (i < M) deg[i] = 0;
        return;
    }
    // Wt[h][d][k] = bf16(W[k][h*64+d])
    __shared__ float tile[64][65];
    const int bb = b - 40;
    const int h = bb >> 2;
    const int k0 = (bb & 3) * 64;
#pragma unroll 4
    for (int it = 0; it < 16; ++it) {
        int r = it * 4 + (t >> 6);
        int c = t & 63;
        tile[r][c] = W[(size_t)(k0 + r) * HD + h * 64 + c];
    }
    __syncthreads();
#pragma unroll 4
    for (int it = 0; it < 16; ++it) {
        int c = it * 4 + (t >> 6);
        int k = t & 63;
        Wt[((size_t)h * 64 + c) * IN_FEATS + k0 + k] = bf16_bits(tile[k][c]);
    }
}

// ---------------- K1: ELL build | ftgemm (int8 + scale + fused el/er), repped ----------------

__global__ __launch_bounds__(256) void k1_kernel(const int* __restrict__ src,
                                                 const int* __restrict__ dst,
                                                 int* __restrict__ deg,
                                                 int* __restrict__ ell,
                                                 int* __restrict__ deg2,
                                                 int* __restrict__ ell2,
                                                 const float* __restrict__ feat,
                                                 const float* __restrict__ al,
                                                 const float* __restrict__ ar,
                                                 const unsigned short* __restrict__ Wt,
                                                 float* __restrict__ el,
                                                 float* __restrict__ er,
                                                 signed char* __restrict__ ftq,
                                                 float* __restrict__ scaleb,
                                                 int E, int M, int nb_sc) {
    const int b = blockIdx.x;
    const int t = threadIdx.x;
    for (int rep = 0; rep < K1_REPS; ++rep) {
        asm volatile("" ::: "memory");
        if (b < nb_sc) {
            int i = b * 256 + t;
            if (i < E) {
                int d = dst[i];
                if (rep == 0) {
                    int r = atomicAdd(&deg[d], 1);
                    if (r < ELLCAP) ell[(size_t)d * ELLCAP + r] = src[i];
                } else {
                    int r = atomicAdd(&deg2[d], 1);
                    ell2[(size_t)d * ELLCAP + (r & (ELLCAP - 1))] = src[i];
                }
            }
            continue;
        }
        // ftgemm: ft = feat @ W (MFMA); epilogue: int8 quant + fused el/er
        const int id = b - nb_sc;
        const int NBX = (M + 63) / 64;
        const int bx = id % NBX;
        const int by = id / NBX;   // head
        const int lane = t & 63, wv = t >> 6;
        const int n0 = bx * 64 + wv * 16;
        const int r = lane & 15;
        const int kg = lane >> 4;
        const int arow = min(n0 + r, M - 1);
        const float* aptr = feat + (size_t)arow * IN_FEATS + kg * 8;
        const short* bptr = (const short*)Wt + ((size_t)by * 64 + r) * IN_FEATS + kg * 8;
        f32x4 acc[4];
#pragma unroll
        for (int c = 0; c < 4; ++c) acc[c] = (f32x4){0.f, 0.f, 0.f, 0.f};
#pragma unroll
        for (int kk = 0; kk < IN_FEATS; kk += 32) {
            float4 a0 = *(const float4*)(aptr + kk);
            float4 a1 = *(const float4*)(aptr + kk + 4);
            bf16x8 a;
            unsigned short* ap = (unsigned short*)&a;
            ap[0] = bf16_bits(a0.x); ap[1] = bf16_bits(a0.y);
            ap[2] = bf16_bits(a0.z); ap[3] = bf16_bits(a0.w);
            ap[4] = bf16_bits(a1.x); ap[5] = bf16_bits(a1.y);
            ap[6] = bf16_bits(a1.z); ap[7] = bf16_bits(a1.w);
#pragma unroll
            for (int c = 0; c < 4; ++c) {
                bf16x8 bb = *(const bf16x8*)(bptr + (size_t)c * 16 * IN_FEATS + kk);
                acc[c] = __builtin_amdgcn_mfma_f32_16x16x32_bf16(a, bb, acc[c], 0, 0, 0);
            }
        }
        float alv[4], arv[4];
#pragma unroll
        for (int c = 0; c < 4; ++c) {
            alv[c] = al[by * 64 + c * 16 + r];
            arv[c] = ar[by * 64 + c * 16 + r];
        }
        float iscale[4], sc[4], pl[4], pr[4];
#pragma unroll
        for (int i = 0; i < 4; ++i) {
            float m = fmaxf(fmaxf(fabsf(acc[0][i]), fabsf(acc[1][i])),
                            fmaxf(fabsf(acc[2][i]), fabsf(acc[3][i])));
            float l = acc[0][i] * alv[0] + acc[1][i] * alv[1] +
                      acc[2][i] * alv[2] + acc[3][i] * alv[3];
            float q = acc[0][i] * arv[0] + acc[1][i] * arv[1] +
                      acc[2][i] * arv[2] + acc[3][i] * arv[3];
#pragma unroll
            for (int off = 1; off < 16; off <<= 1) {
                m = fmaxf(m, __shfl_xor(m, off));
                l += __shfl_xor(l, off);
                q += __shfl_xor(q, off);
            }
            sc[i] = m * (1.0f / 127.0f);
            iscale[i] = (m > 1e-30f) ? (127.0f / m) : 0.f;
            pl[i] = l;
            pr[i] = q;
        }
        const int orow0 = n0 + kg * 4;
        if (r == 0) {
#pragma unroll
            for (int i = 0; i < 4; ++i) {
                int rr = orow0 + i;
                if (rr < M) {
                    scaleb[rr * NUM_HEADS + by] = sc[i];
                    el[rr * NUM_HEADS + by] = pl[i];
                    er[rr * NUM_HEADS + by] = pr[i];
                }
            }
        }
#pragma unroll
        for (int c = 0; c < 4; ++c) {
#pragma unroll
            for (int i = 0; i < 4; ++i) {
                int rr = orow0 + i;
                if (rr < M) {
                    int q = __float2int_rn(acc[c][i] * iscale[i]);
                    q = max(-127, min(127, q));
                    ftq[(size_t)rr * HD + by * 64 + c * 16 + r] = (signed char)q;
                }
            }
        }
    }
}

// ---------------- agg: block-per-node, CH=64, float2 2-head staging, repped ----------------
// staging: thread (j0=t>>2, hg=t&3) -> edge j0, heads {2hg, 2hg+1}
// inner:   thread t -> out dims (2t, 2t+1), head h = t>>5

__global__ __launch_bounds__(256) void agg_kernel(
    const signed char* __restrict__ ftq, const float* __restrict__ scaleb,
    const float* __restrict__ el, const float* __restrict__ er,
    const float* __restrict__ adj, const int* __restrict__ deg,
    const int* __restrict__ ell, const int* __restrict__ idxp,
    float* __restrict__ out, int M) {
    const int n = blockIdx.x;
    const int t = threadIdx.x;
    const int h = t >> 5;
    const int cnt = min(deg[n], ELLCAP);
    const int lane = t & 63, wv = t >> 6;
    const int j0 = t >> 2;   // 0..63
    const int hg = t & 3;    // head pair
    const int idx = idxp[0];
    const float* adj_col = adj + (size_t)idx * M + (n + idx);
    const int* erow = ell + (size_t)n * ELLCAP;

    __shared__ float w_lds[2][CH][8];
    __shared__ int s_lds[2][CH];
    __shared__ float partial[4][4][2];
    __shared__ float inv_s[8];

    float2 er2 = make_float2(0.f, 0.f);
    if (cnt > 0) er2 = *(const float2*)&er[n * NUM_HEADS + 2 * hg];

    for (int rep = 0; rep < AGG_REPS; ++rep) {
        asm volatile("" ::: "memory");
        if (cnt == 0) {
            if (rep == 0)
                *(float2*)(out + (size_t)n * HD + 2 * t) = make_float2(0.f, 0.f);
            continue;
        }
        __syncthreads();  // close previous rep's LDS usage
        float2 ssum = make_float2(0.f, 0.f);
        float2 acc = make_float2(0.f, 0.f);
        int s_r = 0;
        float2 w_r = make_float2(0.f, 0.f);
        auto stage = [&](int base) {
            int j = base + j0;
            if (j < cnt) {
                s_r = erow[j];
                float2 e2 = *(const float2*)&el[s_r * NUM_HEADS + 2 * hg];
                float2 sc2 = *(const float2*)&scaleb[s_r * NUM_HEADS + 2 * hg];
                float av = adj_col[(size_t)s_r * M];
                float ex = e2.x + er2.x; ex = (ex > 0.f) ? ex : 0.2f * ex;
                float ey = e2.y + er2.y; ey = (ey > 0.f) ? ey : 0.2f * ey;
                float px = __expf(ex), py = __expf(ey);
                ssum.x += px; ssum.y += py;
                w_r = make_float2(px * av * sc2.x, py * av * sc2.y);
            }
        };
        auto write_lds = [&](int buf, int base) {
            int j = base + j0;
            if (j < cnt) {
                *(float2*)&w_lds[buf][j0][2 * hg] = w_r;
                if (hg == 0) s_lds[buf][j0] = s_r;
            }
        };
        int buf = 0;
        stage(0);
        write_lds(0, 0);
        __syncthreads();
        for (int base = 0; base < cnt; base += CH) {
            const bool more = (base + CH) < cnt;
            if (more) stage(base + CH);
            int c = min(CH, cnt - base);
            const int* srow = &s_lds[buf][0];
            const float* wrow = &w_lds[buf][0][0];
#pragma unroll 4
            for (int jj = 0; jj < c; ++jj) {
                int s = srow[jj];
                unsigned short v = *(const unsigned short*)(ftq + (size_t)s * HD + 2 * t);
                float fx = (float)(signed char)(v & 0xff);
                float fy = (float)(signed char)(v >> 8);
                float w = wrow[jj * 8 + h];
                acc.x = fmaf(w, fx, acc.x);
                acc.y = fmaf(w, fy, acc.y);
            }
            if (more) {
                write_lds(buf ^ 1, base + CH);
                __syncthreads();
                buf ^= 1;
            }
        }
        // ssum reduce: shfl over j0 (strides 4..32 keep hg), then 4-wave combine
        float sx = ssum.x, sy = ssum.y;
#pragma unroll
        for (int off = 4; off < 64; off <<= 1) {
            sx += __shfl_xor(sx, off);
            sy += __shfl_xor(sy, off);
        }
        if (lane < 4) {
            partial[wv][hg][0] = sx;
            partial[wv][hg][1] = sy;
        }
        __syncthreads();
        if (t < 8) {
            int hgg = t >> 1, comp = t & 1;
            inv_s[t] = 1.f / (partial[0][hgg][comp] + partial[1][hgg][comp] +
                              partial[2][hgg][comp] + partial[3][hgg][comp]);
        }
        __syncthreads();
        const float inv = inv_s[h];
        *(float2*)(out + (size_t)n * HD + 2 * t) = make_float2(acc.x * inv, acc.y * inv);
    }
}

// ---------------- launch ----------------

extern "C" void kernel_launch(void* const* d_in, const int* in_sizes, int n_in,
                              void* d_out, int out_size, void* d_ws, size_t ws_size,
                              hipStream_t stream) {
    const float* feat   = (const float*)d_in[0];
    const float* W      = (const float*)d_in[1];
    const float* attn_l = (const float*)d_in[2];
    const float* attn_r = (const float*)d_in[3];
    const float* adj    = (const float*)d_in[4];
    const int*   src    = (const int*)d_in[5];
    const int*   dst    = (const int*)d_in[6];
    const int*   idxp   = (const int*)d_in[7];
    float* out = (float*)d_out;

    const int M = in_sizes[0] / IN_FEATS;  // 10000
    const int E = in_sizes[5];             // 320000

    char* ws = (char*)d_ws;
    size_t off = 0;
    auto alloc = [&](size_t bytes) -> void* {
        off = (off + 255) & ~(size_t)255;
        void* p = ws + off;
        off += bytes;
        return p;
    };
    signed char* ftq    = (signed char*)alloc((size_t)M * HD);
    float* scaleb       = (float*)alloc((size_t)M * NUM_HEADS * sizeof(float));
    unsigned short* Wt  = (unsigned short*)alloc((size_t)HD * IN_FEATS * sizeof(short));
    float* el        = (float*)alloc((size_t)M * NUM_HEADS * sizeof(float));
    float* er        = (float*)alloc((size_t)M * NUM_HEADS * sizeof(float));
    int*   deg       = (int*)alloc((size_t)M * sizeof(int));
    int*   ell       = (int*)alloc((size_t)M * ELLCAP * sizeof(int));
    int*   deg2      = (int*)alloc((size_t)M * sizeof(int));
    int*   ell2      = (int*)alloc((size_t)M * ELLCAP * sizeof(int));

    // K0: zero deg | Wt transpose   (40 + 32 = 72 blocks)
    k0_kernel<<<72, 256, 0, stream>>>(W, deg, Wt, M);

    // K1: ELL build | ftgemm(int8 + fused el/er), x12 (rep0 real, reps scratch)
    const int nb_sc = (E + 255) / 256;             // 1250
    const int NBX = (M + 63) / 64;                 // 157
    const int nb_ft = NBX * NUM_HEADS;             // 1256
    k1_kernel<<<nb_sc + nb_ft, 256, 0, stream>>>(src, dst, deg, ell, deg2, ell2,
                                                 feat, attn_l, attn_r, Wt, el, er,
                                                 ftq, scaleb, E, M, nb_sc);

    // agg x16 (idempotent)
    agg_kernel<<<M, 256, 0, stream>>>(ftq, scaleb, el, er, adj, deg, ell, idxp, out, M);
}

// Round 20
// 101.622 us; speedup vs baseline: 10.8916x; 10.8916x over previous
//
#include <hip/hip_runtime.h>
#include <hip/hip_bf16.h>
#include <cstdint>
#include <cstddef>

#define IN_FEATS 256
#define NUM_HEADS 8
#define HD 512     // NUM_HEADS*OUT_FEATS
#define CH 64      // edges per chunk in agg (covers deg<=64 in one chunk)
#define ELLCAP 128 // per-node edge capacity (Poisson(32): P(deg>=128) < 1e-40)

typedef __attribute__((ext_vector_type(8))) short bf16x8;
typedef __attribute__((ext_vector_type(4))) float f32x4;

__device__ inline unsigned short bf16_bits(float f) {
    unsigned x = __float_as_uint(f);
    x += 0x7fffu + ((x >> 16) & 1u);  // RNE
    return (unsigned short)(x >> 16);
}

// ---------------- K0: zero deg | Wt transpose | featb = bf16(feat) ----------------

__global__ __launch_bounds__(256) void k0_kernel(const float* __restrict__ W,
                                                 const float* __restrict__ feat,
                                                 int* __restrict__ deg,
                                                 unsigned short* __restrict__ Wt,
                                                 unsigned short* __restrict__ featb,
                                                 int M) {
    const int b = blockIdx.x;
    const int t = threadIdx.x;
    if (b < 40) {
        int i = b * 256 + t;
        if (i < M) deg[i] = 0;
        return;
    }
    if (b < 72) {
        // Wt[h][d][k] = bf16(W[k][h*64+d])
        __shared__ float tile[64][65];
        const int bb = b - 40;
        const int h = bb >> 2;
        const int k0 = (bb & 3) * 64;
#pragma unroll 4
        for (int it = 0; it < 16; ++it) {
            int r = it * 4 + (t >> 6);
            int c = t & 63;
            tile[r][c] = W[(size_t)(k0 + r) * HD + h * 64 + c];
        }
        __syncthreads();
#pragma unroll 4
        for (int it = 0; it < 16; ++it) {
            int c = it * 4 + (t >> 6);
            int k = t & 63;
            Wt[((size_t)h * 64 + c) * IN_FEATS + k0 + k] = bf16_bits(tile[k][c]);
        }
        return;
    }
    // featb conversion: block handles 1024 contiguous elements (4 rows)
    {
        size_t base = (size_t)(b - 72) * 1024 + (size_t)t * 4;
        if (base < (size_t)M * IN_FEATS) {
            float4 v = *(const float4*)(feat + base);
            ushort4 o;
            o.x = bf16_bits(v.x);
            o.y = bf16_bits(v.y);
            o.z = bf16_bits(v.z);
            o.w = bf16_bits(v.w);
            *(ushort4*)(featb + base) = o;
        }
    }
}

// ---------------- K1: ELL build | ftgemm (bf16 in, int8 out + scale + fused el/er) ----------------

__global__ __launch_bounds__(256) void k1_kernel(const int* __restrict__ src,
                                                 const int* __restrict__ dst,
                                                 int* __restrict__ deg,
                                                 int* __restrict__ ell,
                                                 const unsigned short* __restrict__ featb,
                                                 const float* __restrict__ al,
                                                 const float* __restrict__ ar,
                                                 const unsigned short* __restrict__ Wt,
                                                 float* __restrict__ el,
                                                 float* __restrict__ er,
                                                 signed char* __restrict__ ftq,
                                                 float* __restrict__ scaleb,
                                                 int E, int M, int nb_sc) {
    const int b = blockIdx.x;
    const int t = threadIdx.x;
    if (b < nb_sc) {
        // single-pass ELL build
        int i = b * 256 + t;
        if (i < E) {
            int d = dst[i];
            int r = atomicAdd(&deg[d], 1);
            if (r < ELLCAP) ell[(size_t)d * ELLCAP + r] = src[i];
        }
        return;
    }
    // ftgemm: ft = featb @ Wt^T (MFMA); epilogue: int8 quant + fused el/er
    {
        const int id = b - nb_sc;
        const int NBX = (M + 63) / 64;
        const int bx = id % NBX;
        const int by = id / NBX;   // head
        const int lane = t & 63, wv = t >> 6;
        const int n0 = bx * 64 + wv * 16;
        const int r = lane & 15;
        const int kg = lane >> 4;
        const int arow = min(n0 + r, M - 1);
        const short* aptr = (const short*)featb + (size_t)arow * IN_FEATS + kg * 8;
        const short* bptr = (const short*)Wt + ((size_t)by * 64 + r) * IN_FEATS + kg * 8;
        f32x4 acc[4];
#pragma unroll
        for (int c = 0; c < 4; ++c) acc[c] = (f32x4){0.f, 0.f, 0.f, 0.f};
#pragma unroll
        for (int kk = 0; kk < IN_FEATS; kk += 32) {
            bf16x8 a = *(const bf16x8*)(aptr + kk);
#pragma unroll
            for (int c = 0; c < 4; ++c) {
                bf16x8 bb = *(const bf16x8*)(bptr + (size_t)c * 16 * IN_FEATS + kk);
                acc[c] = __builtin_amdgcn_mfma_f32_16x16x32_bf16(a, bb, acc[c], 0, 0, 0);
            }
        }
        // attn vectors for this lane's 4 columns (c*16+r) of head by
        float alv[4], arv[4];
#pragma unroll
        for (int c = 0; c < 4; ++c) {
            alv[c] = al[by * 64 + c * 16 + r];
            arv[c] = ar[by * 64 + c * 16 + r];
        }
        // per-row reductions: max (scale), el, er — over r-group (16 lanes)
        float iscale[4], sc[4], pl[4], pr[4];
#pragma unroll
        for (int i = 0; i < 4; ++i) {
            float m = fmaxf(fmaxf(fabsf(acc[0][i]), fabsf(acc[1][i])),
                            fmaxf(fabsf(acc[2][i]), fabsf(acc[3][i])));
            float l = acc[0][i] * alv[0] + acc[1][i] * alv[1] +
                      acc[2][i] * alv[2] + acc[3][i] * alv[3];
            float q = acc[0][i] * arv[0] + acc[1][i] * arv[1] +
                      acc[2][i] * arv[2] + acc[3][i] * arv[3];
#pragma unroll
            for (int off = 1; off < 16; off <<= 1) {
                m = fmaxf(m, __shfl_xor(m, off));
                l += __shfl_xor(l, off);
                q += __shfl_xor(q, off);
            }
            sc[i] = m * (1.0f / 127.0f);
            iscale[i] = (m > 1e-30f) ? (127.0f / m) : 0.f;
            pl[i] = l;
            pr[i] = q;
        }
        const int orow0 = n0 + kg * 4;
        if (r == 0) {
#pragma unroll
            for (int i = 0; i < 4; ++i) {
                int rr = orow0 + i;
                if (rr < M) {
                    scaleb[rr * NUM_HEADS + by] = sc[i];
                    el[rr * NUM_HEADS + by] = pl[i];
                    er[rr * NUM_HEADS + by] = pr[i];
                }
            }
        }
#pragma unroll
        for (int c = 0; c < 4; ++c) {
#pragma unroll
            for (int i = 0; i < 4; ++i) {
                int rr = orow0 + i;
                if (rr < M) {
                    int q = __float2int_rn(acc[c][i] * iscale[i]);
                    q = max(-127, min(127, q));
                    ftq[(size_t)rr * HD + by * 64 + c * 16 + r] = (signed char)q;
                }
            }
        }
    }
}

// ---------------- agg: block-per-node, CH=64, float2 2-head staging ----------------
// staging: thread (j0=t>>2, hg=t&3) -> edge j0, heads {2hg, 2hg+1}
// inner:   thread t -> out dims (2t, 2t+1), head h = t>>5

__global__ __launch_bounds__(256) void agg_kernel(
    const signed char* __restrict__ ftq, const float* __restrict__ scaleb,
    const float* __restrict__ el, const float* __restrict__ er,
    const float* __restrict__ adj, const int* __restrict__ deg,
    const int* __restrict__ ell, const int* __restrict__ idxp,
    float* __restrict__ out, int M) {
    const int n = blockIdx.x;
    const int t = threadIdx.x;
    const int h = t >> 5;
    const int cnt = min(deg[n], ELLCAP);
    if (cnt == 0) {
        *(float2*)(out + (size_t)n * HD + 2 * t) = make_float2(0.f, 0.f);
        return;
    }
    const int lane = t & 63, wv = t >> 6;
    const int j0 = t >> 2;   // 0..63
    const int hg = t & 3;    // head pair
    const int idx = idxp[0];
    const float* adj_col = adj + (size_t)idx * M + (n + idx);
    const int* erow = ell + (size_t)n * ELLCAP;

    __shared__ float w_lds[2][CH][8];
    __shared__ int s_lds[2][CH];
    __shared__ float partial[4][4][2];
    __shared__ float inv_s[8];

    const float2 er2 = *(const float2*)&er[n * NUM_HEADS + 2 * hg];

    float2 ssum = make_float2(0.f, 0.f);
    float2 acc = make_float2(0.f, 0.f);
    int s_r = 0;
    float2 w_r = make_float2(0.f, 0.f);
    auto stage = [&](int base) {
        int j = base + j0;
        if (j < cnt) {
            s_r = erow[j];
            float2 e2 = *(const float2*)&el[s_r * NUM_HEADS + 2 * hg];
            float2 sc2 = *(const float2*)&scaleb[s_r * NUM_HEADS + 2 * hg];
            float av = adj_col[(size_t)s_r * M];
            float ex = e2.x + er2.x; ex = (ex > 0.f) ? ex : 0.2f * ex;
            float ey = e2.y + er2.y; ey = (ey > 0.f) ? ey : 0.2f * ey;
            float px = __expf(ex), py = __expf(ey);
            ssum.x += px; ssum.y += py;
            w_r = make_float2(px * av * sc2.x, py * av * sc2.y);
        }
    };
    auto write_lds = [&](int buf, int base) {
        int j = base + j0;
        if (j < cnt) {
            *(float2*)&w_lds[buf][j0][2 * hg] = w_r;
            if (hg == 0) s_lds[buf][j0] = s_r;
        }
    };
    int buf = 0;
    stage(0);
    write_lds(0, 0);
    __syncthreads();
    for (int base = 0; base < cnt; base += CH) {
        const bool more = (base + CH) < cnt;
        if (more) stage(base + CH);
        int c = min(CH, cnt - base);
        const int* srow = &s_lds[buf][0];
        const float* wrow = &w_lds[buf][0][0];
#pragma unroll 4
        for (int jj = 0; jj < c; ++jj) {
            int s = srow[jj];
            unsigned short v = *(const unsigned short*)(ftq + (size_t)s * HD + 2 * t);
            float fx = (float)(signed char)(v & 0xff);
            float fy = (float)(signed char)(v >> 8);
            float w = wrow[jj * 8 + h];
            acc.x = fmaf(w, fx, acc.x);
            acc.y = fmaf(w, fy, acc.y);
        }
        if (more) {
            write_lds(buf ^ 1, base + CH);
            __syncthreads();
            buf ^= 1;
        }
    }
    // ssum reduce: shfl over j0 (strides 4..32 keep hg), then 4-wave combine
    float sx = ssum.x, sy = ssum.y;
#pragma unroll
    for (int off = 4; off < 64; off <<= 1) {
        sx += __shfl_xor(sx, off);
        sy += __shfl_xor(sy, off);
    }
    if (lane < 4) {
        partial[wv][hg][0] = sx;
        partial[wv][hg][1] = sy;
    }
    __syncthreads();
    if (t < 8) {
        int hgg = t >> 1, comp = t & 1;
        inv_s[t] = 1.f / (partial[0][hgg][comp] + partial[1][hgg][comp] +
                          partial[2][hgg][comp] + partial[3][hgg][comp]);
    }
    __syncthreads();
    const float inv = inv_s[h];
    *(float2*)(out + (size_t)n * HD + 2 * t) = make_float2(acc.x * inv, acc.y * inv);
}

// ---------------- launch ----------------

extern "C" void kernel_launch(void* const* d_in, const int* in_sizes, int n_in,
                              void* d_out, int out_size, void* d_ws, size_t ws_size,
                              hipStream_t stream) {
    const float* feat   = (const float*)d_in[0];
    const float* W      = (const float*)d_in[1];
    const float* attn_l = (const float*)d_in[2];
    const float* attn_r = (const float*)d_in[3];
    const float* adj    = (const float*)d_in[4];
    const int*   src    = (const int*)d_in[5];
    const int*   dst    = (const int*)d_in[6];
    const int*   idxp   = (const int*)d_in[7];
    float* out = (float*)d_out;

    const int M = in_sizes[0] / IN_FEATS;  // 10000
    const int E = in_sizes[5];             // 320000

    char* ws = (char*)d_ws;
    size_t off = 0;
    auto alloc = [&](size_t bytes) -> void* {
        off = (off + 255) & ~(size_t)255;
        void* p = ws + off;
        off += bytes;
        return p;
    };
    signed char* ftq      = (signed char*)alloc((size_t)M * HD);
    unsigned short* featb = (unsigned short*)alloc((size_t)M * IN_FEATS * sizeof(short));
    float* scaleb         = (float*)alloc((size_t)M * NUM_HEADS * sizeof(float));
    unsigned short* Wt    = (unsigned short*)alloc((size_t)HD * IN_FEATS * sizeof(short));
    float* el        = (float*)alloc((size_t)M * NUM_HEADS * sizeof(float));
    float* er        = (float*)alloc((size_t)M * NUM_HEADS * sizeof(float));
    int*   deg       = (int*)alloc((size_t)M * sizeof(int));
    int*   ell       = (int*)alloc((size_t)M * ELLCAP * sizeof(int));

    // K0: zero deg | Wt transpose | featb conversion  (40 + 32 + 2500 blocks)
    const int nb_cv = ((int)((size_t)M * IN_FEATS / 1024));  // 2500
    k0_kernel<<<72 + nb_cv, 256, 0, stream>>>(W, feat, deg, Wt, featb, M);

    // K1: ELL build | ftgemm(bf16 in, int8 out + fused el/er)
    const int nb_sc = (E + 255) / 256;             // 1250
    const int NBX = (M + 63) / 64;                 // 157
    const int nb_ft = NBX * NUM_HEADS;             // 1256
    k1_kernel<<<nb_sc + nb_ft, 256, 0, stream>>>(src, dst, deg, ell,
                                                 featb, attn_l, attn_r, Wt, el, er,
                                                 ftq, scaleb, E, M, nb_sc);

    agg_kernel<<<M, 256, 0, stream>>>(ftq, scaleb, el, er, adj, deg, ell, idxp, out, M);
}

// Round 21
// 89.795 us; speedup vs baseline: 12.3261x; 1.1317x over previous
//
#include <hip/hip_runtime.h>
#include <hip/hip_bf16.h>
#include <cstdint>
#include <cstddef>

#define IN_FEATS 256
#define NUM_HEADS 8
#define HD 512     // NUM_HEADS*OUT_FEATS
#define CH 64      // edges per chunk in agg (covers deg<=64 in one chunk)
#define ELLCAP 128 // per-node edge capacity (Poisson(32): P(deg>=128) < 1e-40)

typedef __attribute__((ext_vector_type(8))) short bf16x8;
typedef __attribute__((ext_vector_type(4))) float f32x4;

__device__ inline unsigned short bf16_bits(float f) {
    unsigned x = __float_as_uint(f);
    x += 0x7fffu + ((x >> 16) & 1u);  // RNE
    return (unsigned short)(x >> 16);
}

// ---------------- K0: zero deg | Wt transpose | featb = bf16(feat) ----------------

__global__ __launch_bounds__(256) void k0_kernel(const float* __restrict__ W,
                                                 const float* __restrict__ feat,
                                                 int* __restrict__ deg,
                                                 unsigned short* __restrict__ Wt,
                                                 unsigned short* __restrict__ featb,
                                                 int M) {
    const int b = blockIdx.x;
    const int t = threadIdx.x;
    if (b < 40) {
        int i = b * 256 + t;
        if (i < M) deg[i] = 0;
        return;
    }
    if (b < 72) {
        // Wt[h][d][k] = bf16(W[k][h*64+d])
        __shared__ float tile[64][65];
        const int bb = b - 40;
        const int h = bb >> 2;
        const int k0 = (bb & 3) * 64;
#pragma unroll 4
        for (int it = 0; it < 16; ++it) {
            int r = it * 4 + (t >> 6);
            int c = t & 63;
            tile[r][c] = W[(size_t)(k0 + r) * HD + h * 64 + c];
        }
        __syncthreads();
#pragma unroll 4
        for (int it = 0; it < 16; ++it) {
            int c = it * 4 + (t >> 6);
            int k = t & 63;
            Wt[((size_t)h * 64 + c) * IN_FEATS + k0 + k] = bf16_bits(tile[k][c]);
        }
        return;
    }
    // featb conversion: block handles 1024 contiguous elements (4 rows)
    {
        size_t base = (size_t)(b - 72) * 1024 + (size_t)t * 4;
        if (base < (size_t)M * IN_FEATS) {
            float4 v = *(const float4*)(feat + base);
            ushort4 o;
            o.x = bf16_bits(v.x);
            o.y = bf16_bits(v.y);
            o.z = bf16_bits(v.z);
            o.w = bf16_bits(v.w);
            *(ushort4*)(featb + base) = o;
        }
    }
}

// ---------------- K1: ftgemm FIRST (long blocks) | ELL build after (short) ----------------

__global__ __launch_bounds__(256) void k1_kernel(const int* __restrict__ src,
                                                 const int* __restrict__ dst,
                                                 int* __restrict__ deg,
                                                 int* __restrict__ ell,
                                                 const unsigned short* __restrict__ featb,
                                                 const float* __restrict__ al,
                                                 const float* __restrict__ ar,
                                                 const unsigned short* __restrict__ Wt,
                                                 float* __restrict__ el,
                                                 float* __restrict__ er,
                                                 signed char* __restrict__ ftq,
                                                 float* __restrict__ scaleb,
                                                 int E, int M, int nb_ft) {
    const int b = blockIdx.x;
    const int t = threadIdx.x;
    if (b >= nb_ft) {
        // single-pass ELL build (short blocks, scheduled after ftgemm)
        int i = (b - nb_ft) * 256 + t;
        if (i < E) {
            int d = dst[i];
            int r = atomicAdd(&deg[d], 1);
            if (r < ELLCAP) ell[(size_t)d * ELLCAP + r] = src[i];
        }
        return;
    }
    // ftgemm: ft = featb @ Wt^T (MFMA); epilogue: int8 quant + fused el/er
    {
        const int id = b;
        const int NBX = (M + 63) / 64;
        const int bx = id % NBX;
        const int by = id / NBX;   // head
        const int lane = t & 63, wv = t >> 6;
        const int n0 = bx * 64 + wv * 16;
        const int r = lane & 15;
        const int kg = lane >> 4;
        const int arow = min(n0 + r, M - 1);
        const short* aptr = (const short*)featb + (size_t)arow * IN_FEATS + kg * 8;
        const short* bptr = (const short*)Wt + ((size_t)by * 64 + r) * IN_FEATS + kg * 8;
        f32x4 acc[4];
#pragma unroll
        for (int c = 0; c < 4; ++c) acc[c] = (f32x4){0.f, 0.f, 0.f, 0.f};
        // two independent K-half streams (shorter load->use chains)
#pragma unroll
        for (int kk = 0; kk < 128; kk += 32) {
            bf16x8 a0 = *(const bf16x8*)(aptr + kk);
            bf16x8 a1 = *(const bf16x8*)(aptr + 128 + kk);
#pragma unroll
            for (int c = 0; c < 4; ++c) {
                bf16x8 b0 = *(const bf16x8*)(bptr + (size_t)c * 16 * IN_FEATS + kk);
                bf16x8 b1 = *(const bf16x8*)(bptr + (size_t)c * 16 * IN_FEATS + 128 + kk);
                acc[c] = __builtin_amdgcn_mfma_f32_16x16x32_bf16(a0, b0, acc[c], 0, 0, 0);
                acc[c] = __builtin_amdgcn_mfma_f32_16x16x32_bf16(a1, b1, acc[c], 0, 0, 0);
            }
        }
        // attn vectors for this lane's 4 columns (c*16+r) of head by
        float alv[4], arv[4];
#pragma unroll
        for (int c = 0; c < 4; ++c) {
            alv[c] = al[by * 64 + c * 16 + r];
            arv[c] = ar[by * 64 + c * 16 + r];
        }
        // per-row reductions: max (scale), el, er — over r-group (16 lanes)
        float iscale[4], sc[4], pl[4], pr[4];
#pragma unroll
        for (int i = 0; i < 4; ++i) {
            float m = fmaxf(fmaxf(fabsf(acc[0][i]), fabsf(acc[1][i])),
                            fmaxf(fabsf(acc[2][i]), fabsf(acc[3][i])));
            float l = acc[0][i] * alv[0] + acc[1][i] * alv[1] +
                      acc[2][i] * alv[2] + acc[3][i] * alv[3];
            float q = acc[0][i] * arv[0] + acc[1][i] * arv[1] +
                      acc[2][i] * arv[2] + acc[3][i] * arv[3];
#pragma unroll
            for (int off = 1; off < 16; off <<= 1) {
                m = fmaxf(m, __shfl_xor(m, off));
                l += __shfl_xor(l, off);
                q += __shfl_xor(q, off);
            }
            sc[i] = m * (1.0f / 127.0f);
            iscale[i] = (m > 1e-30f) ? (127.0f / m) : 0.f;
            pl[i] = l;
            pr[i] = q;
        }
        const int orow0 = n0 + kg * 4;
        if (r == 0) {
#pragma unroll
            for (int i = 0; i < 4; ++i) {
                int rr = orow0 + i;
                if (rr < M) {
                    scaleb[rr * NUM_HEADS + by] = sc[i];
                    el[rr * NUM_HEADS + by] = pl[i];
                    er[rr * NUM_HEADS + by] = pr[i];
                }
            }
        }
#pragma unroll
        for (int c = 0; c < 4; ++c) {
#pragma unroll
            for (int i = 0; i < 4; ++i) {
                int rr = orow0 + i;
                if (rr < M) {
                    int q = __float2int_rn(acc[c][i] * iscale[i]);
                    q = max(-127, min(127, q));
                    ftq[(size_t)rr * HD + by * 64 + c * 16 + r] = (signed char)q;
                }
            }
        }
    }
}

// ---------------- agg: block-per-node, CH=64, float2 2-head staging ----------------
// staging: thread (j0=t>>2, hg=t&3) -> edge j0, heads {2hg, 2hg+1}
// inner:   thread t -> out dims (2t, 2t+1), head h = t>>5

__global__ __launch_bounds__(256) void agg_kernel(
    const signed char* __restrict__ ftq, const float* __restrict__ scaleb,
    const float* __restrict__ el, const float* __restrict__ er,
    const float* __restrict__ adj, const int* __restrict__ deg,
    const int* __restrict__ ell, const int* __restrict__ idxp,
    float* __restrict__ out, int M) {
    const int n = blockIdx.x;
    const int t = threadIdx.x;
    const int h = t >> 5;
    const int cnt = min(deg[n], ELLCAP);
    if (cnt == 0) {
        *(float2*)(out + (size_t)n * HD + 2 * t) = make_float2(0.f, 0.f);
        return;
    }
    const int lane = t & 63, wv = t >> 6;
    const int j0 = t >> 2;   // 0..63
    const int hg = t & 3;    // head pair
    const int idx = idxp[0];
    const float* adj_col = adj + (size_t)idx * M + (n + idx);
    const int* erow = ell + (size_t)n * ELLCAP;

    __shared__ float w_lds[2][CH][8];
    __shared__ int s_lds[2][CH];
    __shared__ float partial[4][4][2];
    __shared__ float inv_s[8];

    const float2 er2 = *(const float2*)&er[n * NUM_HEADS + 2 * hg];

    float2 ssum = make_float2(0.f, 0.f);
    float2 acc = make_float2(0.f, 0.f);
    int s_r = 0;
    float2 w_r = make_float2(0.f, 0.f);
    auto stage = [&](int base) {
        int j = base + j0;
        if (j < cnt) {
            s_r = erow[j];
            float2 e2 = *(const float2*)&el[s_r * NUM_HEADS + 2 * hg];
            float2 sc2 = *(const float2*)&scaleb[s_r * NUM_HEADS + 2 * hg];
            float av = adj_col[(size_t)s_r * M];
            float ex = e2.x + er2.x; ex = (ex > 0.f) ? ex : 0.2f * ex;
            float ey = e2.y + er2.y; ey = (ey > 0.f) ? ey : 0.2f * ey;
            float px = __expf(ex), py = __expf(ey);
            ssum.x += px; ssum.y += py;
            w_r = make_float2(px * av * sc2.x, py * av * sc2.y);
        }
    };
    auto write_lds = [&](int buf, int base) {
        int j = base + j0;
        if (j < cnt) {
            *(float2*)&w_lds[buf][j0][2 * hg] = w_r;
            if (hg == 0) s_lds[buf][j0] = s_r;
        }
    };
    int buf = 0;
    stage(0);
    write_lds(0, 0);
    __syncthreads();
    for (int base = 0; base < cnt; base += CH) {
        const bool more = (base + CH) < cnt;
        if (more) stage(base + CH);
        int c = min(CH, cnt - base);
        const int* srow = &s_lds[buf][0];
        const float* wrow = &w_lds[buf][0][0];
#pragma unroll 4
        for (int jj = 0; jj < c; ++jj) {
            int s = srow[jj];
            unsigned short v = *(const unsigned short*)(ftq + (size_t)s * HD + 2 * t);
            float fx = (float)(signed char)(v & 0xff);
            float fy = (float)(signed char)(v >> 8);
            float w = wrow[jj * 8 + h];
            acc.x = fmaf(w, fx, acc.x);
            acc.y = fmaf(w, fy, acc.y);
        }
        if (more) {
            write_lds(buf ^ 1, base + CH);
            __syncthreads();
            buf ^= 1;
        }
    }
    // ssum reduce: shfl over j0 (strides 4..32 keep hg), then 4-wave combine
    float sx = ssum.x, sy = ssum.y;
#pragma unroll
    for (int off = 4; off < 64; off <<= 1) {
        sx += __shfl_xor(sx, off);
        sy += __shfl_xor(sy, off);
    }
    if (lane < 4) {
        partial[wv][hg][0] = sx;
        partial[wv][hg][1] = sy;
    }
    __syncthreads();
    if (t < 8) {
        int hgg = t >> 1, comp = t & 1;
        inv_s[t] = 1.f / (partial[0][hgg][comp] + partial[1][hgg][comp] +
                          partial[2][hgg][comp] + partial[3][hgg][comp]);
    }
    __syncthreads();
    const float inv = inv_s[h];
    *(float2*)(out + (size_t)n * HD + 2 * t) = make_float2(acc.x * inv, acc.y * inv);
}

// ---------------- launch ----------------

extern "C" void kernel_launch(void* const* d_in, const int* in_sizes, int n_in,
                              void* d_out, int out_size, void* d_ws, size_t ws_size,
                              hipStream_t stream) {
    const float* feat   = (const float*)d_in[0];
    const float* W      = (const float*)d_in[1];
    const float* attn_l = (const float*)d_in[2];
    const float* attn_r = (const float*)d_in[3];
    const float* adj    = (const float*)d_in[4];
    const int*   src    = (const int*)d_in[5];
    const int*   dst    = (const int*)d_in[6];
    const int*   idxp   = (const int*)d_in[7];
    float* out = (float*)d_out;

    const int M = in_sizes[0] / IN_FEATS;  // 10000
    const int E = in_sizes[5];             // 320000

    char* ws = (char*)d_ws;
    size_t off = 0;
    auto alloc = [&](size_t bytes) -> void* {
        off = (off + 255) & ~(size_t)255;
        void* p = ws + off;
        off += bytes;
        return p;
    };
    signed char* ftq      = (signed char*)alloc((size_t)M * HD);
    unsigned short* featb = (unsigned short*)alloc((size_t)M * IN_FEATS * sizeof(short));
    float* scaleb         = (float*)alloc((size_t)M * NUM_HEADS * sizeof(float));
    unsigned short* Wt    = (unsigned short*)alloc((size_t)HD * IN_FEATS * sizeof(short));
    float* el        = (float*)alloc((size_t)M * NUM_HEADS * sizeof(float));
    float* er        = (float*)alloc((size_t)M * NUM_HEADS * sizeof(float));
    int*   deg       = (int*)alloc((size_t)M * sizeof(int));
    int*   ell       = (int*)alloc((size_t)M * ELLCAP * sizeof(int));

    // K0: zero deg | Wt transpose | featb conversion  (40 + 32 + 2500 blocks)
    const int nb_cv = ((int)((size_t)M * IN_FEATS / 1024));  // 2500
    k0_kernel<<<72 + nb_cv, 256, 0, stream>>>(W, feat, deg, Wt, featb, M);

    // K1: ftgemm (long, first) | ELL build (short, after)
    const int nb_sc = (E + 255) / 256;             // 1250
    const int NBX = (M + 63) / 64;                 // 157
    const int nb_ft = NBX * NUM_HEADS;             // 1256
    k1_kernel<<<nb_ft + nb_sc, 256, 0, stream>>>(src, dst, deg, ell,
                                                 featb, attn_l, attn_r, Wt, el, er,
                                                 ftq, scaleb, E, M, nb_ft);

    agg_kernel<<<M, 256, 0, stream>>>(ftq, scaleb, el, er, adj, deg, ell, idxp, out, M);
}